// Round 15
// baseline (388.802 us; speedup 1.0000x reference)
//
#include <hip/hip_runtime.h>

typedef unsigned int u32;
typedef unsigned short u16;

#define NPTS 120000
#define N1PTS 15000
#define NCLSS 17
#define NSTRIPE 16

static inline int cdiv(int a, int b) { return (a + b - 1) / b; }

typedef __attribute__((ext_vector_type(8))) short bf16x8;
typedef __attribute__((ext_vector_type(4))) float f32x4;

// bf16 helpers (storage-only bf16; math fp32)
__device__ __forceinline__ float bflo(u32 u) { return __uint_as_float(u << 16); }
__device__ __forceinline__ float bfhi(u32 u) { return __uint_as_float(u & 0xFFFF0000u); }
__device__ __forceinline__ u32 f2bf(float f) {   // RNE
    u32 u = __float_as_uint(f);
    return (u + 0x7FFFu + ((u >> 16) & 1u)) >> 16;
}
__device__ __forceinline__ u32 pack2(float a, float b) { return f2bf(a) | (f2bf(b) << 16); }

__device__ __forceinline__ f32x4 mfma16(bf16x8 a, uint4 b, f32x4 c) {
    return __builtin_amdgcn_mfma_f32_16x16x32_bf16(a, __builtin_bit_cast(bf16x8, b), c, 0, 0, 0);
}

// ---------------- nbr transpose: nbrT[k*M + p] = nbr[p*K + k] ----------------
template<int K>
__global__ __launch_bounds__(256) void transpose_nbr(
    const int* __restrict__ nbr, int* __restrict__ nbrT, int M)
{
    __shared__ int tile[256][K + 1];
    int p0 = blockIdx.x * 256;
    int t = threadIdx.x;
    int np = M - p0; if (np > 256) np = 256;
    int total = np * K;
    for (int i = t; i < total; i += 256) {
        int lp = i / K, k = i - lp * K;
        tile[lp][k] = nbr[(size_t)p0 * K + i];
    }
    __syncthreads();
    if (t < np) {
#pragma unroll
        for (int k = 0; k < K; ++k)
            nbrT[(size_t)k * M + p0 + t] = tile[t][k];
    }
}

// ---------------- weight -> B-fragment conversion (hi/lo bf16 split) ----------------
struct WbArgs {
    const float* src[8];
    uint4* dst[8];
    int CINF[8];
    int COFF[8];
    int K2[8];    // 2*K
};

__global__ __launch_bounds__(64) void convert_wb(WbArgs a) {
    int j = blockIdx.y;
    int s2 = blockIdx.x;
    if (s2 >= a.K2[j]) return;
    int lane = threadIdx.x;
    int k = s2 >> 1, tile = s2 & 1;
    int c = a.COFF[j] + (lane >> 4) * 8;
    int o = tile * 16 + (lane & 15);
    const float* w = a.src[j] + ((size_t)k * a.CINF[j] + c) * 32 + o;
    u32 hw[4], lw[4];
#pragma unroll
    for (int q = 0; q < 4; ++q) {
        float w0 = w[(2 * q) * 32], w1 = w[(2 * q + 1) * 32];
        u32 h0 = f2bf(w0), h1 = f2bf(w1);
        float r0 = w0 - __uint_as_float(h0 << 16);
        float r1 = w1 - __uint_as_float(h1 << 16);
        hw[q] = h0 | (h1 << 16);
        lw[q] = f2bf(r0) | (f2bf(r1) << 16);
    }
    uint4 hv; hv.x = hw[0]; hv.y = hw[1]; hv.z = hw[2]; hv.w = hw[3];
    uint4 lv; lv.x = lw[0]; lv.y = lw[1]; lv.z = lw[2]; lv.w = lw[3];
    a.dst[j][(size_t)(s2 * 2 + 0) * 64 + lane] = hv;
    a.dst[j][(size_t)(s2 * 2 + 1) * 64 + lane] = lv;
}

// ---------------- conv_part: k-range partial conv, fp32-chained accumulation ----------------
// 16 waves x 16 points; weights+idx in LDS; DEPTH-6 gather prefetch; barrier-free k-loop.
// MODE 0: acc=0, write fp32 T.  MODE 1: acc=T, write fp32 T.
// MODE 2: acc=T, write bf16 out + striped stats (butterfly, no LDS atomics).
template<int KB, int MODE>
__global__ __launch_bounds__(1024, 8) void conv_part(
    const u16* __restrict__ src, const int* __restrict__ nbrTk,
    const uint4* __restrict__ wb, float* __restrict__ T,
    u16* __restrict__ out, float* __restrict__ stats, int M)
{
    __shared__ uint4 wl[KB * 256];
    __shared__ int il[KB * 256];
    __shared__ float red[15][64];
    int tid = threadIdx.x;
    int lane = tid & 63, wid = tid >> 6;
    int p0 = blockIdx.x * 256 + wid * 16;
    int row = lane & 15, hi4 = lane >> 4;
    int lpt = wid * 16 + row;
    int col = lane & 15;
    const uint4 z4 = {0u, 0u, 0u, 0u};

    for (int i = tid; i < KB * 256; i += 1024) wl[i] = wb[i];
    for (int i = tid; i < KB * 256; i += 1024) {
        int k = i >> 8, pl = i & 255;
        int pp = blockIdx.x * 256 + pl;
        il[i] = (pp < M) ? nbrTk[(size_t)k * M + pp] : -1;
    }

    f32x4 acc0, acc1;
    if (MODE >= 1) {
#pragma unroll
        for (int r = 0; r < 4; ++r) {
            int pp = p0 + hi4 * 4 + r;
            int ps = pp < M ? pp : 0;
            acc0[r] = T[(size_t)ps * 32 + col];
            acc1[r] = T[(size_t)ps * 32 + 16 + col];
        }
    } else {
        acc0 = {0.f, 0.f, 0.f, 0.f};
        acc1 = {0.f, 0.f, 0.f, 0.f};
    }

    __syncthreads();

    auto gld = [&](int k) -> uint4 {
        int idx = il[(k << 8) + lpt];
        int j = idx >= 0 ? idx : 0;
        uint4 v = reinterpret_cast<const uint4*>(src + (size_t)j * 32)[hi4];
        u32 m = (idx >= 0) ? 0xFFFFFFFFu : 0u;
        uint4 r; r.x = v.x & m; r.y = v.y & m; r.z = v.z & m; r.w = v.w & m;
        return r;
    };

    // depth-6 pipeline: maximize outstanding misses per wave
    uint4 g0 = gld(0);
    uint4 g1 = (KB > 1) ? gld(1) : z4;
    uint4 g2 = (KB > 2) ? gld(2) : z4;
    uint4 g3 = (KB > 3) ? gld(3) : z4;
    uint4 g4 = (KB > 4) ? gld(4) : z4;
    uint4 g5 = (KB > 5) ? gld(5) : z4;

#pragma unroll 1
    for (int k = 0; k < KB; ++k) {
        uint4 gn = (k + 6 < KB) ? gld(k + 6) : z4;
        const uint4* bl = &wl[k * 256];
        bf16x8 a = __builtin_bit_cast(bf16x8, g0);
        acc0 = mfma16(a, bl[lane], acc0);
        acc0 = mfma16(a, bl[64 + lane], acc0);
        acc1 = mfma16(a, bl[128 + lane], acc1);
        acc1 = mfma16(a, bl[192 + lane], acc1);
        g0 = g1; g1 = g2; g2 = g3; g3 = g4; g4 = g5; g5 = gn;
    }

    if (MODE <= 1) {
#pragma unroll
        for (int r = 0; r < 4; ++r) {
            int pp = p0 + hi4 * 4 + r;
            if (pp < M) {
                T[(size_t)pp * 32 + col] = acc0[r];
                T[(size_t)pp * 32 + 16 + col] = acc1[r];
            }
        }
        return;
    }

    // MODE 2: bf16 store + striped stats
#pragma unroll
    for (int r = 0; r < 4; ++r) {
        int pp = p0 + hi4 * 4 + r;
        if (pp < M) {
            out[(size_t)pp * 32 + col] = (u16)f2bf(acc0[r]);
            out[(size_t)pp * 32 + 16 + col] = (u16)f2bf(acc1[r]);
        }
    }
    float s0 = 0.f, q0 = 0.f, s1 = 0.f, q1 = 0.f;
#pragma unroll
    for (int r = 0; r < 4; ++r) {
        s0 += acc0[r]; q0 += acc0[r] * acc0[r];
        s1 += acc1[r]; q1 += acc1[r] * acc1[r];
    }
#pragma unroll
    for (int m = 16; m <= 32; m <<= 1) {
        s0 += __shfl_xor(s0, m, 64); q0 += __shfl_xor(q0, m, 64);
        s1 += __shfl_xor(s1, m, 64); q1 += __shfl_xor(q1, m, 64);
    }
    float val = (lane < 16) ? s0 : (lane < 32) ? s1 : (lane < 48) ? q0 : q1;
    if (wid > 0) red[wid - 1][lane] = val;
    __syncthreads();
    if (wid == 0) {
        float t = val;
#pragma unroll
        for (int w = 0; w < 15; ++w) t += red[w][lane];
        atomicAdd(&stats[((blockIdx.x & (NSTRIPE - 1)) << 6) + lane], t);
    }
}

// ---------------- conv_blk8: full K=8 conv, bf16 out + striped stats (depth-6) ----------------
__global__ __launch_bounds__(1024, 8) void conv_blk8(
    const u16* __restrict__ src, const int* __restrict__ nbrT,
    const uint4* __restrict__ wb, u16* __restrict__ out,
    float* __restrict__ stats, int M)
{
    constexpr int K = 8;
    __shared__ uint4 wl[K * 256];
    __shared__ int il[K * 256];
    __shared__ float red[15][64];
    int tid = threadIdx.x;
    int lane = tid & 63, wid = tid >> 6;
    int p0 = blockIdx.x * 256 + wid * 16;
    int row = lane & 15, hi4 = lane >> 4;
    int lpt = wid * 16 + row;
    const uint4 z4 = {0u, 0u, 0u, 0u};

    for (int i = tid; i < K * 256; i += 1024) wl[i] = wb[i];
    for (int i = tid; i < K * 256; i += 1024) {
        int k = i >> 8, pl = i & 255;
        int pp = blockIdx.x * 256 + pl;
        il[i] = (pp < M) ? nbrT[(size_t)k * M + pp] : -1;
    }

    f32x4 acc0 = {0.f, 0.f, 0.f, 0.f};
    f32x4 acc1 = {0.f, 0.f, 0.f, 0.f};

    __syncthreads();

    auto gld = [&](int k) -> uint4 {
        int idx = il[(k << 8) + lpt];
        int j = idx >= 0 ? idx : 0;
        uint4 v = reinterpret_cast<const uint4*>(src + (size_t)j * 32)[hi4];
        u32 m = (idx >= 0) ? 0xFFFFFFFFu : 0u;
        uint4 r; r.x = v.x & m; r.y = v.y & m; r.z = v.z & m; r.w = v.w & m;
        return r;
    };

    uint4 g0 = gld(0);
    uint4 g1 = gld(1);
    uint4 g2 = gld(2);
    uint4 g3 = gld(3);
    uint4 g4 = gld(4);
    uint4 g5 = gld(5);

#pragma unroll 1
    for (int k = 0; k < K; ++k) {
        uint4 gn = (k + 6 < K) ? gld(k + 6) : z4;
        const uint4* bl = &wl[k * 256];
        bf16x8 a = __builtin_bit_cast(bf16x8, g0);
        acc0 = mfma16(a, bl[lane], acc0);
        acc0 = mfma16(a, bl[64 + lane], acc0);
        acc1 = mfma16(a, bl[128 + lane], acc1);
        acc1 = mfma16(a, bl[192 + lane], acc1);
        g0 = g1; g1 = g2; g2 = g3; g3 = g4; g4 = g5; g5 = gn;
    }

#pragma unroll
    for (int r = 0; r < 4; ++r) {
        int pp = p0 + hi4 * 4 + r;
        if (pp < M) {
            out[(size_t)pp * 32 + (lane & 15)] = (u16)f2bf(acc0[r]);
            out[(size_t)pp * 32 + 16 + (lane & 15)] = (u16)f2bf(acc1[r]);
        }
    }

    float s0 = 0.f, q0 = 0.f, s1 = 0.f, q1 = 0.f;
#pragma unroll
    for (int r = 0; r < 4; ++r) {
        s0 += acc0[r]; q0 += acc0[r] * acc0[r];
        s1 += acc1[r]; q1 += acc1[r] * acc1[r];
    }
#pragma unroll
    for (int m = 16; m <= 32; m <<= 1) {
        s0 += __shfl_xor(s0, m, 64); q0 += __shfl_xor(q0, m, 64);
        s1 += __shfl_xor(s1, m, 64); q1 += __shfl_xor(q1, m, 64);
    }
    float val = (lane < 16) ? s0 : (lane < 32) ? s1 : (lane < 48) ? q0 : q1;
    if (wid > 0) red[wid - 1][lane] = val;
    __syncthreads();
    if (wid == 0) {
        float t = val;
#pragma unroll
        for (int w = 0; w < 15; ++w) t += red[w][lane];
        atomicAdd(&stats[((blockIdx.x & (NSTRIPE - 1)) << 6) + lane], t);
    }
}

// ---------------- conv_mfma: 4-wave version for small N1 grids ----------------
template<int K>
__global__ __launch_bounds__(256, 6) void conv_mfma(
    const u16* __restrict__ src, const int* __restrict__ nbrT,
    const uint4* __restrict__ wb, u16* __restrict__ out,
    float* __restrict__ stats, int M)
{
    constexpr int KS = K;
    constexpr int NCH = (KS + 1) / 2;
    __shared__ uint4 wlds[2][512];
    __shared__ float red[4][64];

    int tid = threadIdx.x;
    int lane = tid & 63, wid = tid >> 6;
    int p0 = blockIdx.x * 64 + wid * 16;
    int row = lane & 15, hi4 = lane >> 4;
    int p = p0 + row;
    bool rowok = p < M;
    const uint4 z4 = {0u, 0u, 0u, 0u};

    f32x4 acc0 = {0.f, 0.f, 0.f, 0.f};
    f32x4 acc1 = {0.f, 0.f, 0.f, 0.f};

    {
        uint4 a0 = wb[tid], a1 = wb[256 + tid];
        wlds[0][tid] = a0; wlds[0][256 + tid] = a1;
    }
    uint4 av0 = z4, av1 = z4;
    {
        int iA = -1, iB = -1;
        if (rowok) {
            iA = nbrT[p];
            if (KS > 1) iB = nbrT[(size_t)M + p];
        }
        if (iA >= 0) av0 = reinterpret_cast<const uint4*>(src + (size_t)iA * 32)[hi4];
        if (KS > 1 && iB >= 0) av1 = reinterpret_cast<const uint4*>(src + (size_t)iB * 32)[hi4];
    }

    uint4 wr0 = z4, wr1 = z4;
#pragma unroll 1
    for (int c = 0; c < NCH; ++c) {
        bool last = (c + 1 >= NCH);
        if (!last) {
            wr0 = wb[(size_t)(c + 1) * 512 + tid];
            wr1 = wb[(size_t)(c + 1) * 512 + 256 + tid];
        }
        int nA = -1, nB = -1;
        if (!last && rowok) {
            int s0 = 2 * c + 2;
            nA = nbrT[(size_t)s0 * M + p];
            if (s0 + 1 < KS) nB = nbrT[(size_t)(s0 + 1) * M + p];
        }
        asm volatile("s_waitcnt lgkmcnt(0)" ::: "memory");
        __builtin_amdgcn_s_barrier();
        asm volatile("" ::: "memory");
        uint4 nav0 = z4, nav1 = z4;
        if (nA >= 0) nav0 = reinterpret_cast<const uint4*>(src + (size_t)nA * 32)[hi4];
        if (nB >= 0) nav1 = reinterpret_cast<const uint4*>(src + (size_t)nB * 32)[hi4];

        const uint4* bl = wlds[c & 1];
        {
            bf16x8 a = __builtin_bit_cast(bf16x8, av0);
            acc0 = mfma16(a, bl[lane], acc0);
            acc0 = mfma16(a, bl[64 + lane], acc0);
            acc1 = mfma16(a, bl[128 + lane], acc1);
            acc1 = mfma16(a, bl[192 + lane], acc1);
        }
        if (2 * c + 1 < KS) {
            bf16x8 a = __builtin_bit_cast(bf16x8, av1);
            acc0 = mfma16(a, bl[256 + lane], acc0);
            acc0 = mfma16(a, bl[320 + lane], acc0);
            acc1 = mfma16(a, bl[384 + lane], acc1);
            acc1 = mfma16(a, bl[448 + lane], acc1);
        }
        if (!last) {
            wlds[(c + 1) & 1][tid] = wr0;
            wlds[(c + 1) & 1][256 + tid] = wr1;
        }
        av0 = nav0; av1 = nav1;
    }

#pragma unroll
    for (int r = 0; r < 4; ++r) {
        int pp = p0 + hi4 * 4 + r;
        if (pp < M) {
            out[(size_t)pp * 32 + (lane & 15)] = (u16)f2bf(acc0[r]);
            out[(size_t)pp * 32 + 16 + (lane & 15)] = (u16)f2bf(acc1[r]);
        }
    }

    float s0 = 0.f, q0 = 0.f, s1 = 0.f, q1 = 0.f;
#pragma unroll
    for (int r = 0; r < 4; ++r) {
        s0 += acc0[r]; q0 += acc0[r] * acc0[r];
        s1 += acc1[r]; q1 += acc1[r] * acc1[r];
    }
#pragma unroll
    for (int m = 16; m <= 32; m <<= 1) {
        s0 += __shfl_xor(s0, m, 64); q0 += __shfl_xor(q0, m, 64);
        s1 += __shfl_xor(s1, m, 64); q1 += __shfl_xor(q1, m, 64);
    }
    float val = (lane < 16) ? s0 : (lane < 32) ? s1 : (lane < 48) ? q0 : q1;
    red[wid][lane] = val;
    __syncthreads();
    if (wid == 0) {
        float t = red[0][lane] + red[1][lane] + red[2][lane] + red[3][lane];
        atomicAdd(&stats[((blockIdx.x & (NSTRIPE - 1)) << 6) + lane], t);
    }
}

// ---------------- shared scalar epilogue (conv_x3, conv_ds2) — striped stats ----------------
__device__ __forceinline__ void reduce_store_stats(
    float (&acc)[32], int lane, int wid, bool act, int p,
    u16* __restrict__ out, float* __restrict__ sst)
{
    __shared__ float lds[3][64][17];
#pragma unroll
    for (int r = 0; r < 2; ++r) {
        if (wid > 0) {
#pragma unroll
            for (int j = 0; j < 16; ++j) lds[wid - 1][lane][j] = acc[r * 16 + j];
        }
        __syncthreads();
        if (wid == 0) {
#pragma unroll
            for (int w = 0; w < 3; ++w)
#pragma unroll
                for (int j = 0; j < 16; ++j) acc[r * 16 + j] += lds[w][lane][j];
        }
        __syncthreads();
    }
    if (wid == 0) {
        if (act) {
            u32 wd[16];
#pragma unroll
            for (int q = 0; q < 16; ++q) wd[q] = pack2(acc[2 * q], acc[2 * q + 1]);
            uint4* dst = reinterpret_cast<uint4*>(out + (size_t)p * 32);
            uint4 v;
            v.x = wd[0];  v.y = wd[1];  v.z = wd[2];  v.w = wd[3];  dst[0] = v;
            v.x = wd[4];  v.y = wd[5];  v.z = wd[6];  v.w = wd[7];  dst[1] = v;
            v.x = wd[8];  v.y = wd[9];  v.z = wd[10]; v.w = wd[11]; dst[2] = v;
            v.x = wd[12]; v.y = wd[13]; v.z = wd[14]; v.w = wd[15]; dst[3] = v;
        } else {
#pragma unroll
            for (int o = 0; o < 32; ++o) acc[o] = 0.f;
        }
        float sel1 = 0.f, sel2 = 0.f;
#pragma unroll
        for (int o = 0; o < 32; ++o) {
            float s1 = acc[o], s2 = acc[o] * acc[o];
#pragma unroll
            for (int m = 1; m <= 32; m <<= 1) { s1 += __shfl_xor(s1, m, 64); s2 += __shfl_xor(s2, m, 64); }
            if (lane == o) sel1 = s1;
            if (lane == o + 32) sel2 = s2;
        }
        atomicAdd(&sst[lane], lane < 32 ? sel1 : sel2);
    }
}

__global__ __launch_bounds__(256, 8) void conv_x3(
    const float* __restrict__ src, const int* __restrict__ nbrT,
    const float* __restrict__ W, u16* __restrict__ out,
    float* __restrict__ stats, int M)
{
    constexpr int K = 27;
    int lane = threadIdx.x & 63;
    int wid = __builtin_amdgcn_readfirstlane(threadIdx.x >> 6);
    int p = blockIdx.x * 64 + lane;
    bool act = p < M;
    constexpr int JMAX = 7;

    float acc[32];
#pragma unroll
    for (int o = 0; o < 32; ++o) acc[o] = 0.f;

    int idxs[JMAX];
#pragma unroll
    for (int j = 0; j < JMAX; ++j) {
        int k = wid + 4 * j;
        idxs[j] = (act && k < K) ? nbrT[(size_t)k * M + p] : -1;
    }
#pragma unroll
    for (int j = 0; j < JMAX; ++j) {
        int k = wid + 4 * j;
        if (k >= K) break;
        int idx = idxs[j];
        if (idx >= 0) {
            const float* __restrict__ xr = src + (size_t)idx * 3;
            const float* __restrict__ wk = W + (size_t)k * 3 * 32;
            float x0 = xr[0], x1 = xr[1], x2 = xr[2];
#pragma unroll
            for (int o = 0; o < 32; ++o) {
                float s = fmaf(x0, wk[o], 0.f);
                s = fmaf(x1, wk[32 + o], s);
                acc[o] += fmaf(x2, wk[64 + o], s);
            }
        }
    }
    reduce_store_stats(acc, lane, wid, act, p, out,
                       stats + ((blockIdx.x & (NSTRIPE - 1)) << 6));
}

// ---------------- ds 1x1 conv from two 32-ch sources (u_bn, x0) ----------------
__global__ __launch_bounds__(256, 4) void conv_ds2(
    const u16* __restrict__ u, const u16* __restrict__ x0,
    const float* __restrict__ W, u16* __restrict__ out,
    float* __restrict__ stats, int M)
{
    int lane = threadIdx.x & 63;
    int wid = __builtin_amdgcn_readfirstlane(threadIdx.x >> 6);
    int p = blockIdx.x * 64 + lane;
    bool act = p < M;

    float acc[32];
#pragma unroll
    for (int o = 0; o < 32; ++o) acc[o] = 0.f;

    if (act) {
        const u16* srcp = (wid < 2) ? u : x0;
        const uint4* xr = reinterpret_cast<const uint4*>(srcp + (size_t)p * 32 + (wid & 1) * 16);
        const float* wk = W + (size_t)wid * 16 * 32;
#pragma unroll
        for (int h = 0; h < 2; ++h) {
            uint4 v = xr[h];
            float xv[8] = { bflo(v.x), bfhi(v.x), bflo(v.y), bfhi(v.y),
                            bflo(v.z), bfhi(v.z), bflo(v.w), bfhi(v.w) };
#pragma unroll
            for (int c = 0; c < 8; ++c)
#pragma unroll
                for (int o = 0; o < 32; ++o)
                    acc[o] = fmaf(xv[c], wk[(h * 8 + c) * 32 + o], acc[o]);
        }
    }
    reduce_store_stats(acc, lane, wid, act, p, out,
                       stats + ((blockIdx.x & (NSTRIPE - 1)) << 6));
}

// ---------------- bn apply: sums 16 stripes once per block, then y = a*x + b ----------------
template<bool RELU>
__global__ __launch_bounds__(256) void bn_apply(
    u16* __restrict__ buf, const float* __restrict__ stats,
    const float* __restrict__ gb, float invM, int total)
{
    __shared__ float ab[64];
    if (threadIdx.x < 32) {
        int c = threadIdx.x;
        float s = 0.f, q = 0.f;
#pragma unroll
        for (int st = 0; st < NSTRIPE; ++st) {
            s += stats[st * 64 + c];
            q += stats[st * 64 + 32 + c];
        }
        float mu = s * invM;
        float var = fmaxf(q * invM - mu * mu, 0.f);
        float a = gb[c] * rsqrtf(var + 1e-5f);
        ab[c] = a;
        ab[32 + c] = gb[32 + c] - mu * a;
    }
    __syncthreads();
    int i = blockIdx.x * 256 + threadIdx.x;
    if (i >= total) return;
    int c0 = (i & 3) * 8;
    uint4 v = reinterpret_cast<uint4*>(buf)[i];
    u32 w[4] = { v.x, v.y, v.z, v.w };
    u32 r[4];
#pragma unroll
    for (int q = 0; q < 4; ++q) {
        int c = c0 + 2 * q;
        float y0 = fmaf(ab[c], bflo(w[q]), ab[32 + c]);
        float y1 = fmaf(ab[c + 1], bfhi(w[q]), ab[32 + c + 1]);
        if (RELU) { y0 = fmaxf(y0, 0.f); y1 = fmaxf(y1, 0.f); }
        r[q] = pack2(y0, y1);
    }
    uint4 o; o.x = r[0]; o.y = r[1]; o.z = r[2]; o.w = r[3];
    reinterpret_cast<uint4*>(buf)[i] = o;
}

// ---------------- attention ----------------
__device__ __forceinline__ void load_row32(const u16* __restrict__ base, int p, float (&nv)[32])
{
    const uint4* xr = reinterpret_cast<const uint4*>(base + (size_t)p * 32);
#pragma unroll
    for (int q = 0; q < 4; ++q) {
        uint4 v = xr[q];
        nv[q * 8 + 0] = bflo(v.x); nv[q * 8 + 1] = bfhi(v.x);
        nv[q * 8 + 2] = bflo(v.y); nv[q * 8 + 3] = bfhi(v.y);
        nv[q * 8 + 4] = bflo(v.z); nv[q * 8 + 5] = bfhi(v.z);
        nv[q * 8 + 6] = bflo(v.w); nv[q * 8 + 7] = bfhi(v.w);
    }
}

__global__ __launch_bounds__(256) void att_logits(
    const u16* __restrict__ net, const float* __restrict__ wi,
    const float* __restrict__ bi, float* __restrict__ lbuf,
    u32* __restrict__ mx, int M)
{
    int p = blockIdx.x * 256 + threadIdx.x;
    float l = -3.0e38f;
    if (p < M) {
        float nv[32];
        load_row32(net, p, nv);
        float s = bi[0];
#pragma unroll
        for (int c = 0; c < 32; ++c) s = fmaf(nv[c], wi[c], s);
        lbuf[p] = s;
        l = s;
    }
#pragma unroll
    for (int m = 1; m <= 32; m <<= 1) l = fmaxf(l, __shfl_xor(l, m, 64));
    if ((threadIdx.x & 63) == 0) {
        u32 b = __float_as_uint(l);
        u32 e = (b & 0x80000000u) ? ~b : (b | 0x80000000u);
        atomicMax(mx, e);
    }
}

__global__ __launch_bounds__(256) void att_accum(
    const u16* __restrict__ net, const float* __restrict__ lbuf,
    float* __restrict__ att, int M)
{
    int p = blockIdx.x * 256 + threadIdx.x;
    int lane = threadIdx.x & 63, wid = threadIdx.x >> 6;
    u32 um = __float_as_uint(att[0]);
    float mx = (um & 0x80000000u) ? __uint_as_float(um ^ 0x80000000u) : __uint_as_float(~um);
    float w = 0.f;
    float nv[32];
#pragma unroll
    for (int c = 0; c < 32; ++c) nv[c] = 0.f;
    if (p < M) {
        w = expf(lbuf[p] - mx);
        load_row32(net, p, nv);
    }
    float sel = 0.f;
#pragma unroll
    for (int c = 0; c < 32; ++c) {
        float s = w * nv[c];
#pragma unroll
        for (int m = 1; m <= 32; m <<= 1) s += __shfl_xor(s, m, 64);
        if (lane == c) sel = s;
    }
    {
        float s = w;
#pragma unroll
        for (int m = 1; m <= 32; m <<= 1) s += __shfl_xor(s, m, 64);
        if (lane == 32) sel = s;
    }
    __shared__ float red[4][33];
    if (lane < 33) red[wid][lane] = sel;
    __syncthreads();
    if (wid == 0 && lane < 33) {
        float t = red[0][lane] + red[1][lane] + red[2][lane] + red[3][lane];
        atomicAdd(lane < 32 ? &att[2 + lane] : &att[1], t);
    }
}

__global__ void att_ctx_k(const float* __restrict__ wk, const float* __restrict__ bk,
                          float* __restrict__ att)
{
    int o = threadIdx.x;
    if (o >= 32) return;
    float invS = 1.0f / att[1];
    float s = bk[o];
#pragma unroll
    for (int c = 0; c < 32; ++c) s = fmaf(att[2 + c] * invS, wk[c * 32 + o], s);
    att[34 + o] = s;
}

__global__ __launch_bounds__(256) void att_out_res(
    const u16* __restrict__ net, const u16* __restrict__ d,
    const float* __restrict__ wv, const float* __restrict__ bv,
    const float* __restrict__ wo, const float* __restrict__ bo,
    const float* __restrict__ att, u16* __restrict__ r, int M)
{
    int p = blockIdx.x * 256 + threadIdx.x;
    if (p >= M) return;
    float nv[32];
    load_row32(net, p, nv);
    float vv[32];
#pragma unroll
    for (int o = 0; o < 32; ++o) {
        float s = bv[o];
#pragma unroll
        for (int c = 0; c < 32; ++c) s = fmaf(nv[c], wv[c * 32 + o], s);
        vv[o] = s * att[34 + o];
    }
    float dv[32];
    load_row32(d, p, dv);
    u32 wd[16];
#pragma unroll
    for (int q = 0; q < 16; ++q) {
        float y[2];
#pragma unroll
        for (int t = 0; t < 2; ++t) {
            int oo = 2 * q + t;
            float s = bo[oo];
#pragma unroll
            for (int o = 0; o < 32; ++o) s = fmaf(vv[o], wo[o * 32 + oo], s);
            y[t] = fmaxf(s + dv[oo], 0.f);
        }
        wd[q] = pack2(y[0], y[1]);
    }
    uint4* dst = reinterpret_cast<uint4*>(r + (size_t)p * 32);
    uint4 v;
    v.x = wd[0];  v.y = wd[1];  v.z = wd[2];  v.w = wd[3];  dst[0] = v;
    v.x = wd[4];  v.y = wd[5];  v.z = wd[6];  v.w = wd[7];  dst[1] = v;
    v.x = wd[8];  v.y = wd[9];  v.z = wd[10]; v.w = wd[11]; dst[2] = v;
    v.x = wd[12]; v.y = wd[13]; v.z = wd[14]; v.w = wd[15]; dst[3] = v;
}

// ---------------- final: y = relu(bn(net2) + bn(ds)); out = y@Wcls + bcls ----------------
__global__ __launch_bounds__(256) void final_cls(
    const u16* __restrict__ net2, const u16* __restrict__ dsr,
    const float* __restrict__ st7, const float* __restrict__ st8,
    const float* __restrict__ gb7, const float* __restrict__ gb8,
    const float* __restrict__ wcls, const float* __restrict__ bcls,
    float* __restrict__ outp, float invM, int M)
{
    __shared__ float ab7[64], ab8[64];
    if (threadIdx.x < 64) {
        int c = threadIdx.x & 31;
        const float* st = (threadIdx.x < 32) ? st7 : st8;
        const float* g  = (threadIdx.x < 32) ? gb7 : gb8;
        float* abp      = (threadIdx.x < 32) ? ab7 : ab8;
        float s = 0.f, q = 0.f;
#pragma unroll
        for (int k = 0; k < NSTRIPE; ++k) {
            s += st[k * 64 + c];
            q += st[k * 64 + 32 + c];
        }
        float mu = s * invM;
        float var = fmaxf(q * invM - mu * mu, 0.f);
        float a = g[c] * rsqrtf(var + 1e-5f);
        abp[c] = a;
        abp[32 + c] = g[32 + c] - mu * a;
    }
    __syncthreads();
    int p = blockIdx.x * 256 + threadIdx.x;
    if (p >= M) return;
    float nv[32], dv[32];
    load_row32(net2, p, nv);
    load_row32(dsr, p, dv);
    float y[32];
#pragma unroll
    for (int c = 0; c < 32; ++c) {
        float t = fmaf(ab7[c], nv[c], ab7[32 + c]) + fmaf(ab8[c], dv[c], ab8[32 + c]);
        y[c] = fmaxf(t, 0.f);
    }
#pragma unroll
    for (int j = 0; j < NCLSS; ++j) {
        float s = bcls[j];
#pragma unroll
        for (int c = 0; c < 32; ++c) s = fmaf(y[c], wcls[c * NCLSS + j], s);
        outp[(size_t)p * NCLSS + j] = s;
    }
}

// ---------------- host ----------------
extern "C" void kernel_launch(void* const* d_in, const int* in_sizes, int n_in,
                              void* d_out, int out_size, void* d_ws, size_t ws_size,
                              hipStream_t stream)
{
    char* wsb = (char*)d_ws;

    float* ST  = (float*)wsb;                        // 9216 floats + ATT
    float* ATT = ST + 9216;
    float* L   = (float*)(wsb + 65536);              // N1 logits fp32
    const size_t SZN = 7680000ull;                   // N*32*2 bytes
    const size_t SZ1 = 960000ull;                    // N1*32*2 bytes
    u16* A  = (u16*)(wsb + 131072);
    u16* B  = (u16*)(wsb + 131072 + SZN);
    u16* C  = (u16*)(wsb + 131072 + 2 * SZN);
    u16* D  = (u16*)(wsb + 131072 + 2 * SZN + SZ1);
    u16* E  = (u16*)(wsb + 131072 + 2 * SZN + 2 * SZ1);
    u16* G  = (u16*)(wsb + 131072 + 2 * SZN + 3 * SZ1);
    float* T = (float*)(wsb + 131072 + 3 * SZN + 3 * SZ1);       // N*32 fp32 accumulator

    size_t wboff = 131072 + 3 * SZN + 3 * SZ1 + 15360000ull;
    auto wbsz = [](int K) { return (size_t)((K + 1) & ~1) * 4096; };
    uint4* wb_stem1 = (uint4*)(wsb + wboff);         size_t o1 = wboff + wbsz(27);
    uint4* wb_down  = (uint4*)(wsb + o1);            size_t o2 = o1 + wbsz(8);
    uint4* wb_res1  = (uint4*)(wsb + o2);            size_t o3 = o2 + wbsz(27);
    uint4* wb_res2  = (uint4*)(wsb + o3);            size_t o4 = o3 + wbsz(27);
    uint4* wb_up    = (uint4*)(wsb + o4);            size_t o5 = o4 + wbsz(8);
    uint4* wb_f1A   = (uint4*)(wsb + o5);            size_t o6 = o5 + wbsz(27);
    uint4* wb_f1B   = (uint4*)(wsb + o6);            size_t o7 = o6 + wbsz(27);
    uint4* wb_fuse2 = (uint4*)(wsb + o7);            size_t o8 = o7 + wbsz(27);

    int* nbrT0 = (int*)(wsb + o8);                   size_t o9  = o8 + 27ull * NPTS * 4;
    int* nbrTd = (int*)(wsb + o9);                   size_t o10 = o9 + 8ull * N1PTS * 4;
    int* nbrT1 = (int*)(wsb + o10);                  size_t o11 = o10 + 27ull * N1PTS * 4;
    int* nbrTu = (int*)(wsb + o11);

    const float* X        = (const float*)d_in[0];
    const float* Wstem0   = (const float*)d_in[1];
    const float* gb_stem0 = (const float*)d_in[2];
    const float* Wstem1   = (const float*)d_in[3];
    const float* gb_stem1 = (const float*)d_in[4];
    const float* Wdown    = (const float*)d_in[5];
    const float* gb_down  = (const float*)d_in[6];
    const float* Wres1    = (const float*)d_in[7];
    const float* gb_res1  = (const float*)d_in[8];
    const float* Wres2    = (const float*)d_in[9];
    const float* gb_res2  = (const float*)d_in[10];
    const float* wi = (const float*)d_in[11];
    const float* bi = (const float*)d_in[12];
    const float* wk = (const float*)d_in[13];
    const float* bk = (const float*)d_in[14];
    const float* wv = (const float*)d_in[15];
    const float* bv = (const float*)d_in[16];
    const float* wo = (const float*)d_in[17];
    const float* bo = (const float*)d_in[18];
    const float* Wup      = (const float*)d_in[19];
    const float* gb_up    = (const float*)d_in[20];
    const float* Wfuse1   = (const float*)d_in[21];
    const float* gb_fuse1 = (const float*)d_in[22];
    const float* Wfuse2   = (const float*)d_in[23];
    const float* gb_fuse2 = (const float*)d_in[24];
    const float* Wds      = (const float*)d_in[25];
    const float* gb_ds    = (const float*)d_in[26];
    const float* Wcls     = (const float*)d_in[27];
    const float* bcls     = (const float*)d_in[28];

    const int* nbr0     = (const int*)d_in[29];
    const int* nbr_down = (const int*)d_in[30];
    const int* nbr1     = (const int*)d_in[31];
    const int* nbr_up   = (const int*)d_in[32];

    const float invN  = 1.0f / (float)NPTS;
    const float invN1 = 1.0f / (float)N1PTS;

    hipMemsetAsync((void*)ST, 0, (9216 + 66) * sizeof(float), stream);

    hipLaunchKernelGGL((transpose_nbr<27>), dim3(cdiv(NPTS, 256)), dim3(256), 0, stream,
                       nbr0, nbrT0, NPTS);
    hipLaunchKernelGGL((transpose_nbr<8>), dim3(cdiv(N1PTS, 256)), dim3(256), 0, stream,
                       nbr_down, nbrTd, N1PTS);
    hipLaunchKernelGGL((transpose_nbr<27>), dim3(cdiv(N1PTS, 256)), dim3(256), 0, stream,
                       nbr1, nbrT1, N1PTS);
    hipLaunchKernelGGL((transpose_nbr<8>), dim3(cdiv(NPTS, 256)), dim3(256), 0, stream,
                       nbr_up, nbrTu, NPTS);

    {
        WbArgs a;
        a.src[0] = Wstem1; a.dst[0] = wb_stem1; a.CINF[0] = 32; a.COFF[0] = 0;  a.K2[0] = 54;
        a.src[1] = Wdown;  a.dst[1] = wb_down;  a.CINF[1] = 32; a.COFF[1] = 0;  a.K2[1] = 16;
        a.src[2] = Wres1;  a.dst[2] = wb_res1;  a.CINF[2] = 32; a.COFF[2] = 0;  a.K2[2] = 54;
        a.src[3] = Wres2;  a.dst[3] = wb_res2;  a.CINF[3] = 32; a.COFF[3] = 0;  a.K2[3] = 54;
        a.src[4] = Wup;    a.dst[4] = wb_up;    a.CINF[4] = 32; a.COFF[4] = 0;  a.K2[4] = 16;
        a.src[5] = Wfuse1; a.dst[5] = wb_f1A;   a.CINF[5] = 64; a.COFF[5] = 0;  a.K2[5] = 54;
        a.src[6] = Wfuse1; a.dst[6] = wb_f1B;   a.CINF[6] = 64; a.COFF[6] = 32; a.K2[6] = 54;
        a.src[7] = Wfuse2; a.dst[7] = wb_fuse2; a.CINF[7] = 32; a.COFF[7] = 0;  a.K2[7] = 54;
        hipLaunchKernelGGL(convert_wb, dim3(54, 8), dim3(64), 0, stream, a);
    }

    const int gS   = cdiv(NPTS, 64);     // conv_x3, conv_ds2
    const int gB   = cdiv(NPTS, 256);    // conv_part / conv_blk8
    const int gM1  = cdiv(N1PTS, 64);    // conv_mfma N1
    const int gBN  = cdiv(NPTS * 4, 256);
    const int gBN1 = cdiv(N1PTS * 4, 256);
    const int gN1p = cdiv(N1PTS, 256);
    const int gN   = cdiv(NPTS, 256);
    const int KH0 = 14;                  // 27 = 14 + 13 k-split

    // stem
    hipLaunchKernelGGL(conv_x3, dim3(gS), dim3(256), 0, stream,
                       X, nbrT0, Wstem0, A, ST + 0 * 1024, NPTS);
    hipLaunchKernelGGL((bn_apply<true>), dim3(gBN), dim3(256), 0, stream,
                       A, ST + 0 * 1024, gb_stem0, invN, NPTS * 4);
    // stem1: chain 14 + 13
    hipLaunchKernelGGL((conv_part<14, 0>), dim3(gB), dim3(1024), 0, stream,
                       A, nbrT0, wb_stem1, T, (u16*)nullptr, (float*)nullptr, NPTS);
    hipLaunchKernelGGL((conv_part<13, 2>), dim3(gB), dim3(1024), 0, stream,
                       A, nbrT0 + (size_t)KH0 * NPTS, wb_stem1 + KH0 * 256, T, B, ST + 1 * 1024, NPTS);
    hipLaunchKernelGGL((bn_apply<true>), dim3(gBN), dim3(256), 0, stream,
                       B, ST + 1 * 1024, gb_stem1, invN, NPTS * 4);   // B = x0

    // downsample
    hipLaunchKernelGGL((conv_mfma<8>), dim3(gM1), dim3(256), 0, stream,
                       B, nbrTd, wb_down, C, ST + 2 * 1024, N1PTS);
    hipLaunchKernelGGL((bn_apply<true>), dim3(gBN1), dim3(256), 0, stream,
                       C, ST + 2 * 1024, gb_down, invN1, N1PTS * 4);  // C = d

    // residual block convs
    hipLaunchKernelGGL((conv_mfma<27>), dim3(gM1), dim3(256), 0, stream,
                       C, nbrT1, wb_res1, D, ST + 3 * 1024, N1PTS);
    hipLaunchKernelGGL((bn_apply<true>), dim3(gBN1), dim3(256), 0, stream,
                       D, ST + 3 * 1024, gb_res1, invN1, N1PTS * 4);
    hipLaunchKernelGGL((conv_mfma<27>), dim3(gM1), dim3(256), 0, stream,
                       D, nbrT1, wb_res2, E, ST + 4 * 1024, N1PTS);
    hipLaunchKernelGGL((bn_apply<false>), dim3(gBN1), dim3(256), 0, stream,
                       E, ST + 4 * 1024, gb_res2, invN1, N1PTS * 4);  // E = net

    // attention + residual add (writes r into D)
    hipLaunchKernelGGL(att_logits, dim3(gN1p), dim3(256), 0, stream,
                       E, wi, bi, L, (u32*)ATT, N1PTS);
    hipLaunchKernelGGL(att_accum, dim3(gN1p), dim3(256), 0, stream, E, L, ATT, N1PTS);
    hipLaunchKernelGGL(att_ctx_k, dim3(1), dim3(64), 0, stream, wk, bk, ATT);
    hipLaunchKernelGGL(att_out_res, dim3(gN1p), dim3(256), 0, stream,
                       E, C, wv, bv, wo, bo, ATT, D, N1PTS);          // D = r

    // upsample (K=8, src L2-resident)
    hipLaunchKernelGGL(conv_blk8, dim3(gB), dim3(1024), 0, stream,
                       D, nbrTu, wb_up, A, ST + 5 * 1024, NPTS);
    hipLaunchKernelGGL((bn_apply<true>), dim3(gBN), dim3(256), 0, stream,
                       A, ST + 5 * 1024, gb_up, invN, NPTS * 4);      // A = u_bn

    // fuse1: 4 chained partials (cat never materialized); ds independent
    hipLaunchKernelGGL((conv_part<14, 0>), dim3(gB), dim3(1024), 0, stream,
                       A, nbrT0, wb_f1A, T, (u16*)nullptr, (float*)nullptr, NPTS);
    hipLaunchKernelGGL((conv_part<13, 1>), dim3(gB), dim3(1024), 0, stream,
                       A, nbrT0 + (size_t)KH0 * NPTS, wb_f1A + KH0 * 256, T,
                       (u16*)nullptr, (float*)nullptr, NPTS);
    hipLaunchKernelGGL((conv_part<14, 1>), dim3(gB), dim3(1024), 0, stream,
                       B, nbrT0, wb_f1B, T, (u16*)nullptr, (float*)nullptr, NPTS);
    hipLaunchKernelGGL(conv_ds2, dim3(gS), dim3(256), 0, stream,
                       A, B, Wds, G, ST + 8 * 1024, NPTS);            // G = ds raw
    hipLaunchKernelGGL((conv_part<13, 2>), dim3(gB), dim3(1024), 0, stream,
                       B, nbrT0 + (size_t)KH0 * NPTS, wb_f1B + KH0 * 256, T, A, ST + 6 * 1024, NPTS);
    hipLaunchKernelGGL((bn_apply<true>), dim3(gBN), dim3(256), 0, stream,
                       A, ST + 6 * 1024, gb_fuse1, invN, NPTS * 4);   // A = fuse1 bn

    // fuse2: chain 14 + 13
    hipLaunchKernelGGL((conv_part<14, 0>), dim3(gB), dim3(1024), 0, stream,
                       A, nbrT0, wb_fuse2, T, (u16*)nullptr, (float*)nullptr, NPTS);
    hipLaunchKernelGGL((conv_part<13, 2>), dim3(gB), dim3(1024), 0, stream,
                       A, nbrT0 + (size_t)KH0 * NPTS, wb_fuse2 + KH0 * 256, T, B, ST + 7 * 1024, NPTS);  // B = net2 raw

    // final fuse + classifier
    hipLaunchKernelGGL(final_cls, dim3(gN), dim3(256), 0, stream,
                       B, G, ST + 7 * 1024, ST + 8 * 1024, gb_fuse2, gb_ds,
                       Wcls, bcls, (float*)d_out, invN, NPTS);
}

// Round 16
// 375.312 us; speedup vs baseline: 1.0359x; 1.0359x over previous
//
#include <hip/hip_runtime.h>

typedef unsigned int u32;
typedef unsigned short u16;

#define NPTS 120000
#define N1PTS 15000
#define NCLSS 17
#define NSTRIPE 16

static inline int cdiv(int a, int b) { return (a + b - 1) / b; }

typedef __attribute__((ext_vector_type(8))) short bf16x8;
typedef __attribute__((ext_vector_type(4))) float f32x4;

// bf16 helpers (storage-only bf16; math fp32)
__device__ __forceinline__ float bflo(u32 u) { return __uint_as_float(u << 16); }
__device__ __forceinline__ float bfhi(u32 u) { return __uint_as_float(u & 0xFFFF0000u); }
__device__ __forceinline__ u32 f2bf(float f) {   // RNE
    u32 u = __float_as_uint(f);
    return (u + 0x7FFFu + ((u >> 16) & 1u)) >> 16;
}
__device__ __forceinline__ u32 pack2(float a, float b) { return f2bf(a) | (f2bf(b) << 16); }

__device__ __forceinline__ f32x4 mfma16(bf16x8 a, uint4 b, f32x4 c) {
    return __builtin_amdgcn_mfma_f32_16x16x32_bf16(a, __builtin_bit_cast(bf16x8, b), c, 0, 0, 0);
}

// ---------------- nbr transpose: nbrT[k*M + p] = nbr[p*K + k] ----------------
template<int K>
__global__ __launch_bounds__(256) void transpose_nbr(
    const int* __restrict__ nbr, int* __restrict__ nbrT, int M)
{
    __shared__ int tile[256][K + 1];
    int p0 = blockIdx.x * 256;
    int t = threadIdx.x;
    int np = M - p0; if (np > 256) np = 256;
    int total = np * K;
    for (int i = t; i < total; i += 256) {
        int lp = i / K, k = i - lp * K;
        tile[lp][k] = nbr[(size_t)p0 * K + i];
    }
    __syncthreads();
    if (t < np) {
#pragma unroll
        for (int k = 0; k < K; ++k)
            nbrT[(size_t)k * M + p0 + t] = tile[t][k];
    }
}

// ---------------- weight -> B-fragment conversion (hi/lo bf16 split) ----------------
struct WbArgs {
    const float* src[8];
    uint4* dst[8];
    int CINF[8];
    int COFF[8];
    int K2[8];    // 2*K
};

__global__ __launch_bounds__(64) void convert_wb(WbArgs a) {
    int j = blockIdx.y;
    int s2 = blockIdx.x;
    if (s2 >= a.K2[j]) return;
    int lane = threadIdx.x;
    int k = s2 >> 1, tile = s2 & 1;
    int c = a.COFF[j] + (lane >> 4) * 8;
    int o = tile * 16 + (lane & 15);
    const float* w = a.src[j] + ((size_t)k * a.CINF[j] + c) * 32 + o;
    u32 hw[4], lw[4];
#pragma unroll
    for (int q = 0; q < 4; ++q) {
        float w0 = w[(2 * q) * 32], w1 = w[(2 * q + 1) * 32];
        u32 h0 = f2bf(w0), h1 = f2bf(w1);
        float r0 = w0 - __uint_as_float(h0 << 16);
        float r1 = w1 - __uint_as_float(h1 << 16);
        hw[q] = h0 | (h1 << 16);
        lw[q] = f2bf(r0) | (f2bf(r1) << 16);
    }
    uint4 hv; hv.x = hw[0]; hv.y = hw[1]; hv.z = hw[2]; hv.w = hw[3];
    uint4 lv; lv.x = lw[0]; lv.y = lw[1]; lv.z = lw[2]; lv.w = lw[3];
    a.dst[j][(size_t)(s2 * 2 + 0) * 64 + lane] = hv;
    a.dst[j][(size_t)(s2 * 2 + 1) * 64 + lane] = lv;
}

// ---------------- conv_part: k-range partial conv, fp32-chained accumulation ----------------
// 16 waves x 16 points; weights+idx in LDS; depth-3 prefetch; barrier-free k-loop.
// NPH phases over source row ranges (exec-masked predicated gathers): each phase's
// working set = Msrc/NPH rows -> per-XCD L2-resident for bf16 N-tensors at NPH=2.
// MODE 0: acc=0, write fp32 T.  MODE 1: acc=T, write fp32 T.
// MODE 2: acc=T, write bf16 out + striped stats (butterfly, no LDS atomics).
template<int KB, int MODE, int NPH>
__global__ __launch_bounds__(1024, 8) void conv_part(
    const u16* __restrict__ src, const int* __restrict__ nbrTk,
    const uint4* __restrict__ wb, float* __restrict__ T,
    u16* __restrict__ out, float* __restrict__ stats, int M, int Msrc)
{
    __shared__ uint4 wl[KB * 256];
    __shared__ int il[KB * 256];
    __shared__ float red[15][64];
    int tid = threadIdx.x;
    int lane = tid & 63, wid = tid >> 6;
    int p0 = blockIdx.x * 256 + wid * 16;
    int row = lane & 15, hi4 = lane >> 4;
    int lpt = wid * 16 + row;
    int col = lane & 15;
    const uint4 z4 = {0u, 0u, 0u, 0u};

    for (int i = tid; i < KB * 256; i += 1024) wl[i] = wb[i];
    for (int i = tid; i < KB * 256; i += 1024) {
        int k = i >> 8, pl = i & 255;
        int pp = blockIdx.x * 256 + pl;
        il[i] = (pp < M) ? nbrTk[(size_t)k * M + pp] : -1;
    }

    f32x4 acc0, acc1;
    if (MODE >= 1) {
#pragma unroll
        for (int r = 0; r < 4; ++r) {
            int pp = p0 + hi4 * 4 + r;
            int ps = pp < M ? pp : 0;
            acc0[r] = T[(size_t)ps * 32 + col];
            acc1[r] = T[(size_t)ps * 32 + 16 + col];
        }
    } else {
        acc0 = {0.f, 0.f, 0.f, 0.f};
        acc1 = {0.f, 0.f, 0.f, 0.f};
    }

    __syncthreads();

    const int PHSZ = (Msrc + NPH - 1) / NPH;

    auto gld = [&](int k, int lo, int hi) -> uint4 {
        int idx = il[(k << 8) + lpt];
        uint4 r = z4;
        if (idx >= lo && idx < hi)          // exec-masked: requests only for in-range lanes
            r = reinterpret_cast<const uint4*>(src + (size_t)idx * 32)[hi4];
        return r;
    };

#pragma unroll 1
    for (int ph = 0; ph < NPH; ++ph) {
        int lo = (NPH == 1) ? 0 : ph * PHSZ;
        int hi = (NPH == 1) ? 0x7FFFFFFF : lo + PHSZ;
        uint4 g0 = gld(0, lo, hi);
        uint4 g1 = (KB > 1) ? gld(1, lo, hi) : z4;
        uint4 g2 = (KB > 2) ? gld(2, lo, hi) : z4;
#pragma unroll 1
        for (int k = 0; k < KB; ++k) {
            uint4 gn = (k + 3 < KB) ? gld(k + 3, lo, hi) : z4;
            const uint4* bl = &wl[k * 256];
            bf16x8 a = __builtin_bit_cast(bf16x8, g0);
            acc0 = mfma16(a, bl[lane], acc0);
            acc0 = mfma16(a, bl[64 + lane], acc0);
            acc1 = mfma16(a, bl[128 + lane], acc1);
            acc1 = mfma16(a, bl[192 + lane], acc1);
            g0 = g1; g1 = g2; g2 = gn;
        }
    }

    if (MODE <= 1) {
#pragma unroll
        for (int r = 0; r < 4; ++r) {
            int pp = p0 + hi4 * 4 + r;
            if (pp < M) {
                T[(size_t)pp * 32 + col] = acc0[r];
                T[(size_t)pp * 32 + 16 + col] = acc1[r];
            }
        }
        return;
    }

    // MODE 2: bf16 store + striped stats
#pragma unroll
    for (int r = 0; r < 4; ++r) {
        int pp = p0 + hi4 * 4 + r;
        if (pp < M) {
            out[(size_t)pp * 32 + col] = (u16)f2bf(acc0[r]);
            out[(size_t)pp * 32 + 16 + col] = (u16)f2bf(acc1[r]);
        }
    }
    float s0 = 0.f, q0 = 0.f, s1 = 0.f, q1 = 0.f;
#pragma unroll
    for (int r = 0; r < 4; ++r) {
        s0 += acc0[r]; q0 += acc0[r] * acc0[r];
        s1 += acc1[r]; q1 += acc1[r] * acc1[r];
    }
#pragma unroll
    for (int m = 16; m <= 32; m <<= 1) {
        s0 += __shfl_xor(s0, m, 64); q0 += __shfl_xor(q0, m, 64);
        s1 += __shfl_xor(s1, m, 64); q1 += __shfl_xor(q1, m, 64);
    }
    float val = (lane < 16) ? s0 : (lane < 32) ? s1 : (lane < 48) ? q0 : q1;
    if (wid > 0) red[wid - 1][lane] = val;
    __syncthreads();
    if (wid == 0) {
        float t = val;
#pragma unroll
        for (int w = 0; w < 15; ++w) t += red[w][lane];
        atomicAdd(&stats[((blockIdx.x & (NSTRIPE - 1)) << 6) + lane], t);
    }
}

// ---------------- conv_blk8: full K=8 conv, bf16 out + striped stats (depth-3) ----------------
__global__ __launch_bounds__(1024, 8) void conv_blk8(
    const u16* __restrict__ src, const int* __restrict__ nbrT,
    const uint4* __restrict__ wb, u16* __restrict__ out,
    float* __restrict__ stats, int M)
{
    constexpr int K = 8;
    __shared__ uint4 wl[K * 256];
    __shared__ int il[K * 256];
    __shared__ float red[15][64];
    int tid = threadIdx.x;
    int lane = tid & 63, wid = tid >> 6;
    int p0 = blockIdx.x * 256 + wid * 16;
    int row = lane & 15, hi4 = lane >> 4;
    int lpt = wid * 16 + row;
    const uint4 z4 = {0u, 0u, 0u, 0u};

    for (int i = tid; i < K * 256; i += 1024) wl[i] = wb[i];
    for (int i = tid; i < K * 256; i += 1024) {
        int k = i >> 8, pl = i & 255;
        int pp = blockIdx.x * 256 + pl;
        il[i] = (pp < M) ? nbrT[(size_t)k * M + pp] : -1;
    }

    f32x4 acc0 = {0.f, 0.f, 0.f, 0.f};
    f32x4 acc1 = {0.f, 0.f, 0.f, 0.f};

    __syncthreads();

    auto gld = [&](int k) -> uint4 {
        int idx = il[(k << 8) + lpt];
        int j = idx >= 0 ? idx : 0;
        uint4 v = reinterpret_cast<const uint4*>(src + (size_t)j * 32)[hi4];
        u32 m = (idx >= 0) ? 0xFFFFFFFFu : 0u;
        uint4 r; r.x = v.x & m; r.y = v.y & m; r.z = v.z & m; r.w = v.w & m;
        return r;
    };

    uint4 g0 = gld(0);
    uint4 g1 = gld(1);
    uint4 g2 = gld(2);

#pragma unroll 1
    for (int k = 0; k < K; ++k) {
        uint4 gn = (k + 3 < K) ? gld(k + 3) : z4;
        const uint4* bl = &wl[k * 256];
        bf16x8 a = __builtin_bit_cast(bf16x8, g0);
        acc0 = mfma16(a, bl[lane], acc0);
        acc0 = mfma16(a, bl[64 + lane], acc0);
        acc1 = mfma16(a, bl[128 + lane], acc1);
        acc1 = mfma16(a, bl[192 + lane], acc1);
        g0 = g1; g1 = g2; g2 = gn;
    }

#pragma unroll
    for (int r = 0; r < 4; ++r) {
        int pp = p0 + hi4 * 4 + r;
        if (pp < M) {
            out[(size_t)pp * 32 + (lane & 15)] = (u16)f2bf(acc0[r]);
            out[(size_t)pp * 32 + 16 + (lane & 15)] = (u16)f2bf(acc1[r]);
        }
    }

    float s0 = 0.f, q0 = 0.f, s1 = 0.f, q1 = 0.f;
#pragma unroll
    for (int r = 0; r < 4; ++r) {
        s0 += acc0[r]; q0 += acc0[r] * acc0[r];
        s1 += acc1[r]; q1 += acc1[r] * acc1[r];
    }
#pragma unroll
    for (int m = 16; m <= 32; m <<= 1) {
        s0 += __shfl_xor(s0, m, 64); q0 += __shfl_xor(q0, m, 64);
        s1 += __shfl_xor(s1, m, 64); q1 += __shfl_xor(q1, m, 64);
    }
    float val = (lane < 16) ? s0 : (lane < 32) ? s1 : (lane < 48) ? q0 : q1;
    if (wid > 0) red[wid - 1][lane] = val;
    __syncthreads();
    if (wid == 0) {
        float t = val;
#pragma unroll
        for (int w = 0; w < 15; ++w) t += red[w][lane];
        atomicAdd(&stats[((blockIdx.x & (NSTRIPE - 1)) << 6) + lane], t);
    }
}

// ---------------- conv_mfma: 4-wave version for small N1 grids ----------------
template<int K>
__global__ __launch_bounds__(256, 6) void conv_mfma(
    const u16* __restrict__ src, const int* __restrict__ nbrT,
    const uint4* __restrict__ wb, u16* __restrict__ out,
    float* __restrict__ stats, int M)
{
    constexpr int KS = K;
    constexpr int NCH = (KS + 1) / 2;
    __shared__ uint4 wlds[2][512];
    __shared__ float red[4][64];

    int tid = threadIdx.x;
    int lane = tid & 63, wid = tid >> 6;
    int p0 = blockIdx.x * 64 + wid * 16;
    int row = lane & 15, hi4 = lane >> 4;
    int p = p0 + row;
    bool rowok = p < M;
    const uint4 z4 = {0u, 0u, 0u, 0u};

    f32x4 acc0 = {0.f, 0.f, 0.f, 0.f};
    f32x4 acc1 = {0.f, 0.f, 0.f, 0.f};

    {
        uint4 a0 = wb[tid], a1 = wb[256 + tid];
        wlds[0][tid] = a0; wlds[0][256 + tid] = a1;
    }
    uint4 av0 = z4, av1 = z4;
    {
        int iA = -1, iB = -1;
        if (rowok) {
            iA = nbrT[p];
            if (KS > 1) iB = nbrT[(size_t)M + p];
        }
        if (iA >= 0) av0 = reinterpret_cast<const uint4*>(src + (size_t)iA * 32)[hi4];
        if (KS > 1 && iB >= 0) av1 = reinterpret_cast<const uint4*>(src + (size_t)iB * 32)[hi4];
    }

    uint4 wr0 = z4, wr1 = z4;
#pragma unroll 1
    for (int c = 0; c < NCH; ++c) {
        bool last = (c + 1 >= NCH);
        if (!last) {
            wr0 = wb[(size_t)(c + 1) * 512 + tid];
            wr1 = wb[(size_t)(c + 1) * 512 + 256 + tid];
        }
        int nA = -1, nB = -1;
        if (!last && rowok) {
            int s0 = 2 * c + 2;
            nA = nbrT[(size_t)s0 * M + p];
            if (s0 + 1 < KS) nB = nbrT[(size_t)(s0 + 1) * M + p];
        }
        asm volatile("s_waitcnt lgkmcnt(0)" ::: "memory");
        __builtin_amdgcn_s_barrier();
        asm volatile("" ::: "memory");
        uint4 nav0 = z4, nav1 = z4;
        if (nA >= 0) nav0 = reinterpret_cast<const uint4*>(src + (size_t)nA * 32)[hi4];
        if (nB >= 0) nav1 = reinterpret_cast<const uint4*>(src + (size_t)nB * 32)[hi4];

        const uint4* bl = wlds[c & 1];
        {
            bf16x8 a = __builtin_bit_cast(bf16x8, av0);
            acc0 = mfma16(a, bl[lane], acc0);
            acc0 = mfma16(a, bl[64 + lane], acc0);
            acc1 = mfma16(a, bl[128 + lane], acc1);
            acc1 = mfma16(a, bl[192 + lane], acc1);
        }
        if (2 * c + 1 < KS) {
            bf16x8 a = __builtin_bit_cast(bf16x8, av1);
            acc0 = mfma16(a, bl[256 + lane], acc0);
            acc0 = mfma16(a, bl[320 + lane], acc0);
            acc1 = mfma16(a, bl[384 + lane], acc1);
            acc1 = mfma16(a, bl[448 + lane], acc1);
        }
        if (!last) {
            wlds[(c + 1) & 1][tid] = wr0;
            wlds[(c + 1) & 1][256 + tid] = wr1;
        }
        av0 = nav0; av1 = nav1;
    }

#pragma unroll
    for (int r = 0; r < 4; ++r) {
        int pp = p0 + hi4 * 4 + r;
        if (pp < M) {
            out[(size_t)pp * 32 + (lane & 15)] = (u16)f2bf(acc0[r]);
            out[(size_t)pp * 32 + 16 + (lane & 15)] = (u16)f2bf(acc1[r]);
        }
    }

    float s0 = 0.f, q0 = 0.f, s1 = 0.f, q1 = 0.f;
#pragma unroll
    for (int r = 0; r < 4; ++r) {
        s0 += acc0[r]; q0 += acc0[r] * acc0[r];
        s1 += acc1[r]; q1 += acc1[r] * acc1[r];
    }
#pragma unroll
    for (int m = 16; m <= 32; m <<= 1) {
        s0 += __shfl_xor(s0, m, 64); q0 += __shfl_xor(q0, m, 64);
        s1 += __shfl_xor(s1, m, 64); q1 += __shfl_xor(q1, m, 64);
    }
    float val = (lane < 16) ? s0 : (lane < 32) ? s1 : (lane < 48) ? q0 : q1;
    red[wid][lane] = val;
    __syncthreads();
    if (wid == 0) {
        float t = red[0][lane] + red[1][lane] + red[2][lane] + red[3][lane];
        atomicAdd(&stats[((blockIdx.x & (NSTRIPE - 1)) << 6) + lane], t);
    }
}

// ---------------- shared scalar epilogue (conv_x3, conv_ds2) — striped stats ----------------
__device__ __forceinline__ void reduce_store_stats(
    float (&acc)[32], int lane, int wid, bool act, int p,
    u16* __restrict__ out, float* __restrict__ sst)
{
    __shared__ float lds[3][64][17];
#pragma unroll
    for (int r = 0; r < 2; ++r) {
        if (wid > 0) {
#pragma unroll
            for (int j = 0; j < 16; ++j) lds[wid - 1][lane][j] = acc[r * 16 + j];
        }
        __syncthreads();
        if (wid == 0) {
#pragma unroll
            for (int w = 0; w < 3; ++w)
#pragma unroll
                for (int j = 0; j < 16; ++j) acc[r * 16 + j] += lds[w][lane][j];
        }
        __syncthreads();
    }
    if (wid == 0) {
        if (act) {
            u32 wd[16];
#pragma unroll
            for (int q = 0; q < 16; ++q) wd[q] = pack2(acc[2 * q], acc[2 * q + 1]);
            uint4* dst = reinterpret_cast<uint4*>(out + (size_t)p * 32);
            uint4 v;
            v.x = wd[0];  v.y = wd[1];  v.z = wd[2];  v.w = wd[3];  dst[0] = v;
            v.x = wd[4];  v.y = wd[5];  v.z = wd[6];  v.w = wd[7];  dst[1] = v;
            v.x = wd[8];  v.y = wd[9];  v.z = wd[10]; v.w = wd[11]; dst[2] = v;
            v.x = wd[12]; v.y = wd[13]; v.z = wd[14]; v.w = wd[15]; dst[3] = v;
        } else {
#pragma unroll
            for (int o = 0; o < 32; ++o) acc[o] = 0.f;
        }
        float sel1 = 0.f, sel2 = 0.f;
#pragma unroll
        for (int o = 0; o < 32; ++o) {
            float s1 = acc[o], s2 = acc[o] * acc[o];
#pragma unroll
            for (int m = 1; m <= 32; m <<= 1) { s1 += __shfl_xor(s1, m, 64); s2 += __shfl_xor(s2, m, 64); }
            if (lane == o) sel1 = s1;
            if (lane == o + 32) sel2 = s2;
        }
        atomicAdd(&sst[lane], lane < 32 ? sel1 : sel2);
    }
}

__global__ __launch_bounds__(256, 8) void conv_x3(
    const float* __restrict__ src, const int* __restrict__ nbrT,
    const float* __restrict__ W, u16* __restrict__ out,
    float* __restrict__ stats, int M)
{
    constexpr int K = 27;
    int lane = threadIdx.x & 63;
    int wid = __builtin_amdgcn_readfirstlane(threadIdx.x >> 6);
    int p = blockIdx.x * 64 + lane;
    bool act = p < M;
    constexpr int JMAX = 7;

    float acc[32];
#pragma unroll
    for (int o = 0; o < 32; ++o) acc[o] = 0.f;

    int idxs[JMAX];
#pragma unroll
    for (int j = 0; j < JMAX; ++j) {
        int k = wid + 4 * j;
        idxs[j] = (act && k < K) ? nbrT[(size_t)k * M + p] : -1;
    }
#pragma unroll
    for (int j = 0; j < JMAX; ++j) {
        int k = wid + 4 * j;
        if (k >= K) break;
        int idx = idxs[j];
        if (idx >= 0) {
            const float* __restrict__ xr = src + (size_t)idx * 3;
            const float* __restrict__ wk = W + (size_t)k * 3 * 32;
            float x0 = xr[0], x1 = xr[1], x2 = xr[2];
#pragma unroll
            for (int o = 0; o < 32; ++o) {
                float s = fmaf(x0, wk[o], 0.f);
                s = fmaf(x1, wk[32 + o], s);
                acc[o] += fmaf(x2, wk[64 + o], s);
            }
        }
    }
    reduce_store_stats(acc, lane, wid, act, p, out,
                       stats + ((blockIdx.x & (NSTRIPE - 1)) << 6));
}

// ---------------- ds 1x1 conv from two 32-ch sources (u_bn, x0) ----------------
__global__ __launch_bounds__(256, 4) void conv_ds2(
    const u16* __restrict__ u, const u16* __restrict__ x0,
    const float* __restrict__ W, u16* __restrict__ out,
    float* __restrict__ stats, int M)
{
    int lane = threadIdx.x & 63;
    int wid = __builtin_amdgcn_readfirstlane(threadIdx.x >> 6);
    int p = blockIdx.x * 64 + lane;
    bool act = p < M;

    float acc[32];
#pragma unroll
    for (int o = 0; o < 32; ++o) acc[o] = 0.f;

    if (act) {
        const u16* srcp = (wid < 2) ? u : x0;
        const uint4* xr = reinterpret_cast<const uint4*>(srcp + (size_t)p * 32 + (wid & 1) * 16);
        const float* wk = W + (size_t)wid * 16 * 32;
#pragma unroll
        for (int h = 0; h < 2; ++h) {
            uint4 v = xr[h];
            float xv[8] = { bflo(v.x), bfhi(v.x), bflo(v.y), bfhi(v.y),
                            bflo(v.z), bfhi(v.z), bflo(v.w), bfhi(v.w) };
#pragma unroll
            for (int c = 0; c < 8; ++c)
#pragma unroll
                for (int o = 0; o < 32; ++o)
                    acc[o] = fmaf(xv[c], wk[(h * 8 + c) * 32 + o], acc[o]);
        }
    }
    reduce_store_stats(acc, lane, wid, act, p, out,
                       stats + ((blockIdx.x & (NSTRIPE - 1)) << 6));
}

// ---------------- bn apply: sums 16 stripes once per block, then y = a*x + b ----------------
template<bool RELU>
__global__ __launch_bounds__(256) void bn_apply(
    u16* __restrict__ buf, const float* __restrict__ stats,
    const float* __restrict__ gb, float invM, int total)
{
    __shared__ float ab[64];
    if (threadIdx.x < 32) {
        int c = threadIdx.x;
        float s = 0.f, q = 0.f;
#pragma unroll
        for (int st = 0; st < NSTRIPE; ++st) {
            s += stats[st * 64 + c];
            q += stats[st * 64 + 32 + c];
        }
        float mu = s * invM;
        float var = fmaxf(q * invM - mu * mu, 0.f);
        float a = gb[c] * rsqrtf(var + 1e-5f);
        ab[c] = a;
        ab[32 + c] = gb[32 + c] - mu * a;
    }
    __syncthreads();
    int i = blockIdx.x * 256 + threadIdx.x;
    if (i >= total) return;
    int c0 = (i & 3) * 8;
    uint4 v = reinterpret_cast<uint4*>(buf)[i];
    u32 w[4] = { v.x, v.y, v.z, v.w };
    u32 r[4];
#pragma unroll
    for (int q = 0; q < 4; ++q) {
        int c = c0 + 2 * q;
        float y0 = fmaf(ab[c], bflo(w[q]), ab[32 + c]);
        float y1 = fmaf(ab[c + 1], bfhi(w[q]), ab[32 + c + 1]);
        if (RELU) { y0 = fmaxf(y0, 0.f); y1 = fmaxf(y1, 0.f); }
        r[q] = pack2(y0, y1);
    }
    uint4 o; o.x = r[0]; o.y = r[1]; o.z = r[2]; o.w = r[3];
    reinterpret_cast<uint4*>(buf)[i] = o;
}

// ---------------- attention ----------------
__device__ __forceinline__ void load_row32(const u16* __restrict__ base, int p, float (&nv)[32])
{
    const uint4* xr = reinterpret_cast<const uint4*>(base + (size_t)p * 32);
#pragma unroll
    for (int q = 0; q < 4; ++q) {
        uint4 v = xr[q];
        nv[q * 8 + 0] = bflo(v.x); nv[q * 8 + 1] = bfhi(v.x);
        nv[q * 8 + 2] = bflo(v.y); nv[q * 8 + 3] = bfhi(v.y);
        nv[q * 8 + 4] = bflo(v.z); nv[q * 8 + 5] = bfhi(v.z);
        nv[q * 8 + 6] = bflo(v.w); nv[q * 8 + 7] = bfhi(v.w);
    }
}

__global__ __launch_bounds__(256) void att_logits(
    const u16* __restrict__ net, const float* __restrict__ wi,
    const float* __restrict__ bi, float* __restrict__ lbuf,
    u32* __restrict__ mx, int M)
{
    int p = blockIdx.x * 256 + threadIdx.x;
    float l = -3.0e38f;
    if (p < M) {
        float nv[32];
        load_row32(net, p, nv);
        float s = bi[0];
#pragma unroll
        for (int c = 0; c < 32; ++c) s = fmaf(nv[c], wi[c], s);
        lbuf[p] = s;
        l = s;
    }
#pragma unroll
    for (int m = 1; m <= 32; m <<= 1) l = fmaxf(l, __shfl_xor(l, m, 64));
    if ((threadIdx.x & 63) == 0) {
        u32 b = __float_as_uint(l);
        u32 e = (b & 0x80000000u) ? ~b : (b | 0x80000000u);
        atomicMax(mx, e);
    }
}

__global__ __launch_bounds__(256) void att_accum(
    const u16* __restrict__ net, const float* __restrict__ lbuf,
    float* __restrict__ att, int M)
{
    int p = blockIdx.x * 256 + threadIdx.x;
    int lane = threadIdx.x & 63, wid = threadIdx.x >> 6;
    u32 um = __float_as_uint(att[0]);
    float mx = (um & 0x80000000u) ? __uint_as_float(um ^ 0x80000000u) : __uint_as_float(~um);
    float w = 0.f;
    float nv[32];
#pragma unroll
    for (int c = 0; c < 32; ++c) nv[c] = 0.f;
    if (p < M) {
        w = expf(lbuf[p] - mx);
        load_row32(net, p, nv);
    }
    float sel = 0.f;
#pragma unroll
    for (int c = 0; c < 32; ++c) {
        float s = w * nv[c];
#pragma unroll
        for (int m = 1; m <= 32; m <<= 1) s += __shfl_xor(s, m, 64);
        if (lane == c) sel = s;
    }
    {
        float s = w;
#pragma unroll
        for (int m = 1; m <= 32; m <<= 1) s += __shfl_xor(s, m, 64);
        if (lane == 32) sel = s;
    }
    __shared__ float red[4][33];
    if (lane < 33) red[wid][lane] = sel;
    __syncthreads();
    if (wid == 0 && lane < 33) {
        float t = red[0][lane] + red[1][lane] + red[2][lane] + red[3][lane];
        atomicAdd(lane < 32 ? &att[2 + lane] : &att[1], t);
    }
}

__global__ void att_ctx_k(const float* __restrict__ wk, const float* __restrict__ bk,
                          float* __restrict__ att)
{
    int o = threadIdx.x;
    if (o >= 32) return;
    float invS = 1.0f / att[1];
    float s = bk[o];
#pragma unroll
    for (int c = 0; c < 32; ++c) s = fmaf(att[2 + c] * invS, wk[c * 32 + o], s);
    att[34 + o] = s;
}

__global__ __launch_bounds__(256) void att_out_res(
    const u16* __restrict__ net, const u16* __restrict__ d,
    const float* __restrict__ wv, const float* __restrict__ bv,
    const float* __restrict__ wo, const float* __restrict__ bo,
    const float* __restrict__ att, u16* __restrict__ r, int M)
{
    int p = blockIdx.x * 256 + threadIdx.x;
    if (p >= M) return;
    float nv[32];
    load_row32(net, p, nv);
    float vv[32];
#pragma unroll
    for (int o = 0; o < 32; ++o) {
        float s = bv[o];
#pragma unroll
        for (int c = 0; c < 32; ++c) s = fmaf(nv[c], wv[c * 32 + o], s);
        vv[o] = s * att[34 + o];
    }
    float dv[32];
    load_row32(d, p, dv);
    u32 wd[16];
#pragma unroll
    for (int q = 0; q < 16; ++q) {
        float y[2];
#pragma unroll
        for (int t = 0; t < 2; ++t) {
            int oo = 2 * q + t;
            float s = bo[oo];
#pragma unroll
            for (int o = 0; o < 32; ++o) s = fmaf(vv[o], wo[o * 32 + oo], s);
            y[t] = fmaxf(s + dv[oo], 0.f);
        }
        wd[q] = pack2(y[0], y[1]);
    }
    uint4* dst = reinterpret_cast<uint4*>(r + (size_t)p * 32);
    uint4 v;
    v.x = wd[0];  v.y = wd[1];  v.z = wd[2];  v.w = wd[3];  dst[0] = v;
    v.x = wd[4];  v.y = wd[5];  v.z = wd[6];  v.w = wd[7];  dst[1] = v;
    v.x = wd[8];  v.y = wd[9];  v.z = wd[10]; v.w = wd[11]; dst[2] = v;
    v.x = wd[12]; v.y = wd[13]; v.z = wd[14]; v.w = wd[15]; dst[3] = v;
}

// ---------------- final: y = relu(bn(net2) + bn(ds)); out = y@Wcls + bcls ----------------
__global__ __launch_bounds__(256) void final_cls(
    const u16* __restrict__ net2, const u16* __restrict__ dsr,
    const float* __restrict__ st7, const float* __restrict__ st8,
    const float* __restrict__ gb7, const float* __restrict__ gb8,
    const float* __restrict__ wcls, const float* __restrict__ bcls,
    float* __restrict__ outp, float invM, int M)
{
    __shared__ float ab7[64], ab8[64];
    if (threadIdx.x < 64) {
        int c = threadIdx.x & 31;
        const float* st = (threadIdx.x < 32) ? st7 : st8;
        const float* g  = (threadIdx.x < 32) ? gb7 : gb8;
        float* abp      = (threadIdx.x < 32) ? ab7 : ab8;
        float s = 0.f, q = 0.f;
#pragma unroll
        for (int k = 0; k < NSTRIPE; ++k) {
            s += st[k * 64 + c];
            q += st[k * 64 + 32 + c];
        }
        float mu = s * invM;
        float var = fmaxf(q * invM - mu * mu, 0.f);
        float a = g[c] * rsqrtf(var + 1e-5f);
        abp[c] = a;
        abp[32 + c] = g[32 + c] - mu * a;
    }
    __syncthreads();
    int p = blockIdx.x * 256 + threadIdx.x;
    if (p >= M) return;
    float nv[32], dv[32];
    load_row32(net2, p, nv);
    load_row32(dsr, p, dv);
    float y[32];
#pragma unroll
    for (int c = 0; c < 32; ++c) {
        float t = fmaf(ab7[c], nv[c], ab7[32 + c]) + fmaf(ab8[c], dv[c], ab8[32 + c]);
        y[c] = fmaxf(t, 0.f);
    }
#pragma unroll
    for (int j = 0; j < NCLSS; ++j) {
        float s = bcls[j];
#pragma unroll
        for (int c = 0; c < 32; ++c) s = fmaf(y[c], wcls[c * NCLSS + j], s);
        outp[(size_t)p * NCLSS + j] = s;
    }
}

// ---------------- host ----------------
extern "C" void kernel_launch(void* const* d_in, const int* in_sizes, int n_in,
                              void* d_out, int out_size, void* d_ws, size_t ws_size,
                              hipStream_t stream)
{
    char* wsb = (char*)d_ws;

    float* ST  = (float*)wsb;                        // 9216 floats + ATT
    float* ATT = ST + 9216;
    float* L   = (float*)(wsb + 65536);              // N1 logits fp32
    const size_t SZN = 7680000ull;                   // N*32*2 bytes
    const size_t SZ1 = 960000ull;                    // N1*32*2 bytes
    u16* A  = (u16*)(wsb + 131072);
    u16* B  = (u16*)(wsb + 131072 + SZN);
    u16* C  = (u16*)(wsb + 131072 + 2 * SZN);
    u16* D  = (u16*)(wsb + 131072 + 2 * SZN + SZ1);
    u16* E  = (u16*)(wsb + 131072 + 2 * SZN + 2 * SZ1);
    u16* G  = (u16*)(wsb + 131072 + 2 * SZN + 3 * SZ1);
    float* T = (float*)(wsb + 131072 + 3 * SZN + 3 * SZ1);       // N*32 fp32 accumulator

    size_t wboff = 131072 + 3 * SZN + 3 * SZ1 + 15360000ull;
    auto wbsz = [](int K) { return (size_t)((K + 1) & ~1) * 4096; };
    uint4* wb_stem1 = (uint4*)(wsb + wboff);         size_t o1 = wboff + wbsz(27);
    uint4* wb_down  = (uint4*)(wsb + o1);            size_t o2 = o1 + wbsz(8);
    uint4* wb_res1  = (uint4*)(wsb + o2);            size_t o3 = o2 + wbsz(27);
    uint4* wb_res2  = (uint4*)(wsb + o3);            size_t o4 = o3 + wbsz(27);
    uint4* wb_up    = (uint4*)(wsb + o4);            size_t o5 = o4 + wbsz(8);
    uint4* wb_f1A   = (uint4*)(wsb + o5);            size_t o6 = o5 + wbsz(27);
    uint4* wb_f1B   = (uint4*)(wsb + o6);            size_t o7 = o6 + wbsz(27);
    uint4* wb_fuse2 = (uint4*)(wsb + o7);            size_t o8 = o7 + wbsz(27);

    int* nbrT0 = (int*)(wsb + o8);                   size_t o9  = o8 + 27ull * NPTS * 4;
    int* nbrTd = (int*)(wsb + o9);                   size_t o10 = o9 + 8ull * N1PTS * 4;
    int* nbrT1 = (int*)(wsb + o10);                  size_t o11 = o10 + 27ull * N1PTS * 4;
    int* nbrTu = (int*)(wsb + o11);

    const float* X        = (const float*)d_in[0];
    const float* Wstem0   = (const float*)d_in[1];
    const float* gb_stem0 = (const float*)d_in[2];
    const float* Wstem1   = (const float*)d_in[3];
    const float* gb_stem1 = (const float*)d_in[4];
    const float* Wdown    = (const float*)d_in[5];
    const float* gb_down  = (const float*)d_in[6];
    const float* Wres1    = (const float*)d_in[7];
    const float* gb_res1  = (const float*)d_in[8];
    const float* Wres2    = (const float*)d_in[9];
    const float* gb_res2  = (const float*)d_in[10];
    const float* wi = (const float*)d_in[11];
    const float* bi = (const float*)d_in[12];
    const float* wk = (const float*)d_in[13];
    const float* bk = (const float*)d_in[14];
    const float* wv = (const float*)d_in[15];
    const float* bv = (const float*)d_in[16];
    const float* wo = (const float*)d_in[17];
    const float* bo = (const float*)d_in[18];
    const float* Wup      = (const float*)d_in[19];
    const float* gb_up    = (const float*)d_in[20];
    const float* Wfuse1   = (const float*)d_in[21];
    const float* gb_fuse1 = (const float*)d_in[22];
    const float* Wfuse2   = (const float*)d_in[23];
    const float* gb_fuse2 = (const float*)d_in[24];
    const float* Wds      = (const float*)d_in[25];
    const float* gb_ds    = (const float*)d_in[26];
    const float* Wcls     = (const float*)d_in[27];
    const float* bcls     = (const float*)d_in[28];

    const int* nbr0     = (const int*)d_in[29];
    const int* nbr_down = (const int*)d_in[30];
    const int* nbr1     = (const int*)d_in[31];
    const int* nbr_up   = (const int*)d_in[32];

    const float invN  = 1.0f / (float)NPTS;
    const float invN1 = 1.0f / (float)N1PTS;

    hipMemsetAsync((void*)ST, 0, (9216 + 66) * sizeof(float), stream);

    hipLaunchKernelGGL((transpose_nbr<27>), dim3(cdiv(NPTS, 256)), dim3(256), 0, stream,
                       nbr0, nbrT0, NPTS);
    hipLaunchKernelGGL((transpose_nbr<8>), dim3(cdiv(N1PTS, 256)), dim3(256), 0, stream,
                       nbr_down, nbrTd, N1PTS);
    hipLaunchKernelGGL((transpose_nbr<27>), dim3(cdiv(N1PTS, 256)), dim3(256), 0, stream,
                       nbr1, nbrT1, N1PTS);
    hipLaunchKernelGGL((transpose_nbr<8>), dim3(cdiv(NPTS, 256)), dim3(256), 0, stream,
                       nbr_up, nbrTu, NPTS);

    {
        WbArgs a;
        a.src[0] = Wstem1; a.dst[0] = wb_stem1; a.CINF[0] = 32; a.COFF[0] = 0;  a.K2[0] = 54;
        a.src[1] = Wdown;  a.dst[1] = wb_down;  a.CINF[1] = 32; a.COFF[1] = 0;  a.K2[1] = 16;
        a.src[2] = Wres1;  a.dst[2] = wb_res1;  a.CINF[2] = 32; a.COFF[2] = 0;  a.K2[2] = 54;
        a.src[3] = Wres2;  a.dst[3] = wb_res2;  a.CINF[3] = 32; a.COFF[3] = 0;  a.K2[3] = 54;
        a.src[4] = Wup;    a.dst[4] = wb_up;    a.CINF[4] = 32; a.COFF[4] = 0;  a.K2[4] = 16;
        a.src[5] = Wfuse1; a.dst[5] = wb_f1A;   a.CINF[5] = 64; a.COFF[5] = 0;  a.K2[5] = 54;
        a.src[6] = Wfuse1; a.dst[6] = wb_f1B;   a.CINF[6] = 64; a.COFF[6] = 32; a.K2[6] = 54;
        a.src[7] = Wfuse2; a.dst[7] = wb_fuse2; a.CINF[7] = 32; a.COFF[7] = 0;  a.K2[7] = 54;
        hipLaunchKernelGGL(convert_wb, dim3(54, 8), dim3(64), 0, stream, a);
    }

    const int gS   = cdiv(NPTS, 64);     // conv_x3, conv_ds2
    const int gB   = cdiv(NPTS, 256);    // conv_part / conv_blk8
    const int gM1  = cdiv(N1PTS, 64);    // conv_mfma N1
    const int gBN  = cdiv(NPTS * 4, 256);
    const int gBN1 = cdiv(N1PTS * 4, 256);
    const int gN1p = cdiv(N1PTS, 256);
    const int gN   = cdiv(NPTS, 256);
    const int KH0 = 14;                  // 27 = 14 + 13 k-split

    // stem
    hipLaunchKernelGGL(conv_x3, dim3(gS), dim3(256), 0, stream,
                       X, nbrT0, Wstem0, A, ST + 0 * 1024, NPTS);
    hipLaunchKernelGGL((bn_apply<true>), dim3(gBN), dim3(256), 0, stream,
                       A, ST + 0 * 1024, gb_stem0, invN, NPTS * 4);
    // stem1: chain 14 + 13 (NPH=2 phased: src halves L2-resident)
    hipLaunchKernelGGL((conv_part<14, 0, 2>), dim3(gB), dim3(1024), 0, stream,
                       A, nbrT0, wb_stem1, T, (u16*)nullptr, (float*)nullptr, NPTS, NPTS);
    hipLaunchKernelGGL((conv_part<13, 2, 2>), dim3(gB), dim3(1024), 0, stream,
                       A, nbrT0 + (size_t)KH0 * NPTS, wb_stem1 + KH0 * 256, T, B, ST + 1 * 1024, NPTS, NPTS);
    hipLaunchKernelGGL((bn_apply<true>), dim3(gBN), dim3(256), 0, stream,
                       B, ST + 1 * 1024, gb_stem1, invN, NPTS * 4);   // B = x0

    // downsample
    hipLaunchKernelGGL((conv_mfma<8>), dim3(gM1), dim3(256), 0, stream,
                       B, nbrTd, wb_down, C, ST + 2 * 1024, N1PTS);
    hipLaunchKernelGGL((bn_apply<true>), dim3(gBN1), dim3(256), 0, stream,
                       C, ST + 2 * 1024, gb_down, invN1, N1PTS * 4);  // C = d

    // residual block convs
    hipLaunchKernelGGL((conv_mfma<27>), dim3(gM1), dim3(256), 0, stream,
                       C, nbrT1, wb_res1, D, ST + 3 * 1024, N1PTS);
    hipLaunchKernelGGL((bn_apply<true>), dim3(gBN1), dim3(256), 0, stream,
                       D, ST + 3 * 1024, gb_res1, invN1, N1PTS * 4);
    hipLaunchKernelGGL((conv_mfma<27>), dim3(gM1), dim3(256), 0, stream,
                       D, nbrT1, wb_res2, E, ST + 4 * 1024, N1PTS);
    hipLaunchKernelGGL((bn_apply<false>), dim3(gBN1), dim3(256), 0, stream,
                       E, ST + 4 * 1024, gb_res2, invN1, N1PTS * 4);  // E = net

    // attention + residual add (writes r into D)
    hipLaunchKernelGGL(att_logits, dim3(gN1p), dim3(256), 0, stream,
                       E, wi, bi, L, (u32*)ATT, N1PTS);
    hipLaunchKernelGGL(att_accum, dim3(gN1p), dim3(256), 0, stream, E, L, ATT, N1PTS);
    hipLaunchKernelGGL(att_ctx_k, dim3(1), dim3(64), 0, stream, wk, bk, ATT);
    hipLaunchKernelGGL(att_out_res, dim3(gN1p), dim3(256), 0, stream,
                       E, C, wv, bv, wo, bo, ATT, D, N1PTS);          // D = r

    // upsample (K=8, src 0.96 MB already L2-resident)
    hipLaunchKernelGGL(conv_blk8, dim3(gB), dim3(1024), 0, stream,
                       D, nbrTu, wb_up, A, ST + 5 * 1024, NPTS);
    hipLaunchKernelGGL((bn_apply<true>), dim3(gBN), dim3(256), 0, stream,
                       A, ST + 5 * 1024, gb_up, invN, NPTS * 4);      // A = u_bn

    // fuse1: 4 chained partials (cat never materialized); ds independent
    hipLaunchKernelGGL((conv_part<14, 0, 2>), dim3(gB), dim3(1024), 0, stream,
                       A, nbrT0, wb_f1A, T, (u16*)nullptr, (float*)nullptr, NPTS, NPTS);
    hipLaunchKernelGGL((conv_part<13, 1, 2>), dim3(gB), dim3(1024), 0, stream,
                       A, nbrT0 + (size_t)KH0 * NPTS, wb_f1A + KH0 * 256, T,
                       (u16*)nullptr, (float*)nullptr, NPTS, NPTS);
    hipLaunchKernelGGL((conv_part<14, 1, 2>), dim3(gB), dim3(1024), 0, stream,
                       B, nbrT0, wb_f1B, T, (u16*)nullptr, (float*)nullptr, NPTS, NPTS);
    hipLaunchKernelGGL(conv_ds2, dim3(gS), dim3(256), 0, stream,
                       A, B, Wds, G, ST + 8 * 1024, NPTS);            // G = ds raw
    hipLaunchKernelGGL((conv_part<13, 2, 2>), dim3(gB), dim3(1024), 0, stream,
                       B, nbrT0 + (size_t)KH0 * NPTS, wb_f1B + KH0 * 256, T, A, ST + 6 * 1024, NPTS, NPTS);
    hipLaunchKernelGGL((bn_apply<true>), dim3(gBN), dim3(256), 0, stream,
                       A, ST + 6 * 1024, gb_fuse1, invN, NPTS * 4);   // A = fuse1 bn

    // fuse2: chain 14 + 13
    hipLaunchKernelGGL((conv_part<14, 0, 2>), dim3(gB), dim3(1024), 0, stream,
                       A, nbrT0, wb_fuse2, T, (u16*)nullptr, (float*)nullptr, NPTS, NPTS);
    hipLaunchKernelGGL((conv_part<13, 2, 2>), dim3(gB), dim3(1024), 0, stream,
                       A, nbrT0 + (size_t)KH0 * NPTS, wb_fuse2 + KH0 * 256, T, B, ST + 7 * 1024, NPTS, NPTS);  // B = net2 raw

    // final fuse + classifier
    hipLaunchKernelGGL(final_cls, dim3(gN), dim3(256), 0, stream,
                       B, G, ST + 7 * 1024, ST + 8 * 1024, gb_fuse2, gb_ds,
                       Wcls, bcls, (float*)d_out, invN, NPTS);
}